// Round 6
// baseline (170.898 us; speedup 1.0000x reference)
//
#include <hip/hip_runtime.h>

#define BB 256
#define LL 512
#define TT 128
#define CH 16  // staged steps per chunk

typedef _Float16 h2 __attribute__((ext_vector_type(2)));
typedef _Float16 f16x8 __attribute__((ext_vector_type(8)));
typedef float f32x4 __attribute__((ext_vector_type(4)));

#define MFMA16x32(A, B, C) __builtin_amdgcn_mfma_f32_16x16x32_f16((A), (B), (C), 0, 0, 0)

static __device__ inline h2 pkrtz(float a, float b) {
  return __builtin_bit_cast(h2, __builtin_amdgcn_cvt_pkrtz(a, b));
}

// Full-wave max via DPP (VALU pipe only — off the LDS queue).
static __device__ inline float wave_max_dpp(float x) {
  int v = __float_as_int(x);
#define DPP_STEP(ctrl)                                                  \
  {                                                                     \
    int t = __builtin_amdgcn_update_dpp(v, v, (ctrl), 0xf, 0xf, false); \
    x = fmaxf(x, __int_as_float(t));                                    \
    v = __float_as_int(x);                                              \
  }
  DPP_STEP(0x111) DPP_STEP(0x112) DPP_STEP(0x114) DPP_STEP(0x118)
  DPP_STEP(0x142) DPP_STEP(0x143)
#undef DPP_STEP
  return __int_as_float(__builtin_amdgcn_readlane(v, 63));
}

static __device__ inline unsigned expbits(unsigned u) {
  return __float_as_uint(__expf(__uint_as_float(u)));
}

// r5 structure (2 chain waves + 2 stager waves, chunk barriers, exp folded
// at staging, exact pow2 scale bookkeeping) with the 128-dot matvec
// replaced by 32 v_mfma_f32_16x16x32_f16. A operand = 16 IDENTICAL rows of
// the state vector (row-layout-independent broadcast; each lane's A frag =
// one ds_read_b128 of its K-slice from the linear state in LDS). B = E,
// stationary in 32 f16x8 fragments (128 VGPRs). D layout (verified:
// col=lane&15, rows all equal) => every lane holds output j=16n+(lane&15)
// for all 8 tiles; lanes 0-15 store the 128 halves back to LDS.
// Rationale: a solo wave issues 1 instr / 4 cy on CDNA4, so per-step cost
// is ~4cy x instruction count; MFMA cuts the matvec from 128 instrs to 32.
__global__ __launch_bounds__(256)
__attribute__((amdgpu_waves_per_eu(1, 1)))
void crf_fb_kernel(const float* __restrict__ inputs,
                   const float* __restrict__ trans,
                   const float* __restrict__ start_t,
                   const float* __restrict__ end_t,
                   const int* __restrict__ tags,
                   const int* __restrict__ mask,
                   float* __restrict__ diff) {
  const int b = blockIdx.x;
  const int tid = threadIdx.x;
  const int lane = tid & 63;
  const int wid = tid >> 6;

  __shared__ __align__(16) float fbuf[2][CH * TT];  // fwd emissions, exp-folded
  __shared__ __align__(16) float bbuf[2][CH * TT];  // bwd emissions, exp-folded
  __shared__ __align__(16) h2 ef_lds[64];           // fwd state (128 halves)
  __shared__ __align__(16) h2 g_lds[64];            // bwd state (128 halves)
  __shared__ float numA_sh, numB_sh;
  __shared__ int sb_sh;

  // ---- each wave computes len ----
  int lm = 0;
  const int* mk = mask + b * LL;
#pragma unroll
  for (int q = 0; q < LL / 64; ++q) lm += mk[q * 64 + lane];
#pragma unroll
  for (int d = 1; d < 64; d <<= 1) lm += __shfl_xor(lm, d);
  const int len = lm;            // [256, 512]
  const int m = (len - 1) >> 1;  // meeting point; m >= 127
  const int NC = (len - 1 - m + CH - 1) / CH;  // chunks (bwd has max steps)

  const float* erow = inputs + (size_t)b * LL * TT;
  const float2* er2 = (const float2*)erow;

  // stage 16 rows (8 KB), folding exp() so the chain never computes it
  auto STAGE = [&](float* dst, const float* gbase) {
    const uint4* gs = (const uint4*)gbase;
    uint4* ds = (uint4*)dst;
    uint4 v[8];
#pragma unroll
    for (int q = 0; q < 8; ++q) v[q] = gs[q * 64 + lane];
#pragma unroll
    for (int q = 0; q < 8; ++q) {
      uint4 o;
      o.x = expbits(v[q].x);
      o.y = expbits(v[q].y);
      o.z = expbits(v[q].z);
      o.w = expbits(v[q].w);
      ds[q * 64 + lane] = o;
    }
  };

  int S = 0;
  float inv_sc = 1.0f;
  int cur_ex = 0;
  f16x8 EB[8][4];  // E fragments: tile n (out cols 16n..16n+15) x K-chunk c
  const int lg = lane >> 4, lc = lane & 15;

  // ================= prologue =================
  if (wid == 0) {
    // fwd: out j, contract over i.  B[k=i][col=j]:
    // EB[n][c][jj] = exp(trans[32c+8*lg+jj][16n+lc])
#pragma unroll
    for (int n = 0; n < 8; ++n)
#pragma unroll
      for (int c = 0; c < 4; ++c) {
        f16x8 e;
#pragma unroll
        for (int jj = 0; jj < 8; ++jj)
          e[jj] = (_Float16)__expf(trans[(32 * c + 8 * lg + jj) * TT + 16 * n + lc]);
        EB[n][c] = e;
      }
    float2 em0 = er2[lane];
    float f0 = __expf(start_t[2 * lane] + em0.x);
    float f1 = __expf(start_t[2 * lane + 1] + em0.y);
    ef_lds[lane] = pkrtz(f0, f1);
    float mx = wave_max_dpp(fmaxf(f0, f1));
    int exm = (int)((__float_as_uint(mx) >> 23) & 255) - 127;
    inv_sc = __uint_as_float((unsigned)(120 - exm) << 23);
    cur_ex = exm + 7;
  } else if (wid == 1) {
    // bwd: out i, contract over j.  B[k=j][col=i]:
    // EB[n][c][jj] = exp(trans[16n+lc][32c+8*lg+jj])  (contiguous cols)
    const float2* tr2 = (const float2*)trans;
#pragma unroll
    for (int n = 0; n < 8; ++n)
#pragma unroll
      for (int c = 0; c < 4; ++c) {
        int base = (16 * n + lc) * 64 + 16 * c + 4 * lg;
        float2 r0 = tr2[base + 0], r1 = tr2[base + 1];
        float2 r2 = tr2[base + 2], r3 = tr2[base + 3];
        f16x8 e;
        e[0] = (_Float16)__expf(r0.x);
        e[1] = (_Float16)__expf(r0.y);
        e[2] = (_Float16)__expf(r1.x);
        e[3] = (_Float16)__expf(r1.y);
        e[4] = (_Float16)__expf(r2.x);
        e[5] = (_Float16)__expf(r2.y);
        e[6] = (_Float16)__expf(r3.x);
        e[7] = (_Float16)__expf(r3.y);
        EB[n][c] = e;
      }
    float2 em = er2[(size_t)(len - 1) * 64 + lane];
    float g0 = __expf(end_t[2 * lane] + em.x);
    float g1 = __expf(end_t[2 * lane + 1] + em.y);
    g_lds[lane] = pkrtz(g0, g1);
    float mx = wave_max_dpp(fmaxf(g0, g1));
    int exm = (int)((__float_as_uint(mx) >> 23) & 255) - 127;
    inv_sc = __uint_as_float((unsigned)(120 - exm) << 23);
    cur_ex = exm + 7;
  } else if (wid == 2) {
    STAGE(fbuf[0], erow + 1 * TT);  // fwd chunk 0: rows 1..16
    // numerator half A: t in [0, len/2)
    const int* tg = tags + (size_t)b * LL;
    const int hl = len >> 1;
    float sc = 0.f;
    for (int t = lane; t < hl; t += 64) {
      int cu = tg[t];
      sc += erow[(size_t)t * TT + cu];
      if (t >= 1) sc += trans[tg[t - 1] * TT + cu];
    }
    if (lane == 0) sc += start_t[tg[0]];
#pragma unroll
    for (int d = 1; d < 64; d <<= 1) sc += __shfl_xor(sc, d);
    if (lane == 0) numA_sh = sc;
  } else {
    STAGE(bbuf[0], erow + (size_t)(len - 1 - CH) * TT);  // bwd chunk 0
    // numerator half B: t in [len/2, len)
    const int* tg = tags + (size_t)b * LL;
    const int hl = len >> 1;
    float sc = 0.f;
    for (int t = hl + lane; t < len; t += 64) {
      int cu = tg[t];
      sc += erow[(size_t)t * TT + cu];
      sc += trans[tg[t - 1] * TT + cu];
    }
    if (lane == 0) sc += end_t[tg[len - 1]];
#pragma unroll
    for (int d = 1; d < 64; d <<= 1) sc += __shfl_xor(sc, d);
    if (lane == 0) numB_sh = sc;
  }

  __syncthreads();

  const f32x4 z4 = {0.f, 0.f, 0.f, 0.f};

  // ================= chunk loop =================
  for (int c = 0; c < NC; ++c) {
    if (wid == 0) {
      // ---- forward chain steps of chunk c ----
      const float* fb = fbuf[c & 1];
      const uint4* ep = (const uint4*)ef_lds;
      const int tbeg = 1 + CH * c;
      const int tend = min(tbeg + CH - 1, m);
#pragma unroll 1
      for (int t = tbeg; t <= tend; ++t) {
        // A frags: lane's K-slice of the raw state (broadcast b128 reads)
        f16x8 A0 = __builtin_bit_cast(f16x8, ep[0 + lg]);
        f16x8 A1 = __builtin_bit_cast(f16x8, ep[4 + lg]);
        f16x8 A2 = __builtin_bit_cast(f16x8, ep[8 + lg]);
        f16x8 A3 = __builtin_bit_cast(f16x8, ep[12 + lg]);
        float fv[8];
        const int fbase = (t - tbeg) * TT + lc;
#pragma unroll
        for (int n = 0; n < 8; ++n) fv[n] = fb[fbase + 16 * n];
        f32x4 acc[8];
#pragma unroll
        for (int n = 0; n < 8; ++n) acc[n] = MFMA16x32(A0, EB[n][0], z4);
#pragma unroll
        for (int n = 0; n < 8; ++n) acc[n] = MFMA16x32(A1, EB[n][1], acc[n]);
#pragma unroll
        for (int n = 0; n < 8; ++n) acc[n] = MFMA16x32(A2, EB[n][2], acc[n]);
#pragma unroll
        for (int n = 0; n < 8; ++n) acc[n] = MFMA16x32(A3, EB[n][3], acc[n]);
        float w[8];
#pragma unroll
        for (int n = 0; n < 8; ++n) w[n] = acc[n][0] * (fv[n] * inv_sc);
        float wm = w[0];
#pragma unroll
        for (int n = 1; n < 8; ++n) wm = fmaxf(wm, w[n]);
        if (lane < 16) {
          _Float16* sp = (_Float16*)ef_lds;
#pragma unroll
          for (int n = 0; n < 8; ++n) sp[16 * n + lc] = pkrtz(w[n], w[n]).x;
        }
        S += cur_ex;
        float mx = wave_max_dpp(wm);
        int exm = (int)((__float_as_uint(mx) >> 23) & 255) - 127;
        inv_sc = __uint_as_float((unsigned)(120 - exm) << 23);
        cur_ex = exm + 7;
      }
    } else if (wid == 1) {
      // ---- backward chain steps of chunk c ----
      const int thi = len - 2 - CH * c;
      const int lb = len - 1 - CH * (c + 1);  // staged base row
      const int tlo = max(m, lb);
      const float* bbm = bbuf[c & 1];
      const uint4* gp = (const uint4*)g_lds;
#pragma unroll 1
      for (int t = thi; t >= tlo; --t) {
        f16x8 A0 = __builtin_bit_cast(f16x8, gp[0 + lg]);
        f16x8 A1 = __builtin_bit_cast(f16x8, gp[4 + lg]);
        f16x8 A2 = __builtin_bit_cast(f16x8, gp[8 + lg]);
        f16x8 A3 = __builtin_bit_cast(f16x8, gp[12 + lg]);
        float pex[8];
        const int pbase = (t - lb) * TT + lc;
#pragma unroll
        for (int n = 0; n < 8; ++n) pex[n] = bbm[pbase + 16 * n];
        f32x4 acc[8];
#pragma unroll
        for (int n = 0; n < 8; ++n) acc[n] = MFMA16x32(A0, EB[n][0], z4);
#pragma unroll
        for (int n = 0; n < 8; ++n) acc[n] = MFMA16x32(A1, EB[n][1], acc[n]);
#pragma unroll
        for (int n = 0; n < 8; ++n) acc[n] = MFMA16x32(A2, EB[n][2], acc[n]);
#pragma unroll
        for (int n = 0; n < 8; ++n) acc[n] = MFMA16x32(A3, EB[n][3], acc[n]);
        float w[8];
        if (t > m) {  // fold exp(emit_t); at t==m store raw
#pragma unroll
          for (int n = 0; n < 8; ++n) w[n] = acc[n][0] * (pex[n] * inv_sc);
        } else {
#pragma unroll
          for (int n = 0; n < 8; ++n) w[n] = acc[n][0] * inv_sc;
        }
        float wm = w[0];
#pragma unroll
        for (int n = 1; n < 8; ++n) wm = fmaxf(wm, w[n]);
        if (lane < 16) {
          _Float16* sp = (_Float16*)g_lds;
#pragma unroll
          for (int n = 0; n < 8; ++n) sp[16 * n + lc] = pkrtz(w[n], w[n]).x;
        }
        S += cur_ex;
        float mx = wave_max_dpp(wm);
        int exm = (int)((__float_as_uint(mx) >> 23) & 255) - 127;
        inv_sc = __uint_as_float((unsigned)(120 - exm) << 23);
        cur_ex = exm + 7;
      }
    } else if (wid == 2) {
      if (c + 1 < NC) STAGE(fbuf[(c + 1) & 1], erow + (size_t)(1 + CH * (c + 1)) * TT);
    } else {
      if (c + 1 < NC) STAGE(bbuf[(c + 1) & 1], erow + (size_t)(len - 1 - CH * (c + 2)) * TT);
    }
    __syncthreads();
  }

  if (wid == 1 && lane == 0) sb_sh = S;
  __syncthreads();

  if (wid == 0) {
    h2 a = ef_lds[lane];
    h2 g = g_lds[lane];
    float v = (float)a.x * (float)g.x + (float)a.y * (float)g.y;
#pragma unroll
    for (int d = 1; d < 64; d <<= 1) v += __shfl_xor(v, d);
    if (lane == 0) {
      float log_den = (float)(S + sb_sh) * 0.6931471805599453f + __logf(v);
      diff[b] = (numA_sh + numB_sh) - log_den;
    }
  }
}

// Deterministic final reduction over batch.
__global__ void crf_sum_kernel(const float* __restrict__ diff,
                               float* __restrict__ out) {
  const int tid = threadIdx.x;  // 256
  float v = diff[tid];
#pragma unroll
  for (int d = 1; d < 64; d <<= 1) v += __shfl_xor(v, d);
  __shared__ float r[4];
  if ((tid & 63) == 0) r[tid >> 6] = v;
  __syncthreads();
  if (tid == 0) out[0] = r[0] + r[1] + r[2] + r[3];
}

extern "C" void kernel_launch(void* const* d_in, const int* in_sizes, int n_in,
                              void* d_out, int out_size, void* d_ws, size_t ws_size,
                              hipStream_t stream) {
  const float* inputs = (const float*)d_in[0];
  const float* trans = (const float*)d_in[1];
  const float* start_t = (const float*)d_in[2];
  const float* end_t = (const float*)d_in[3];
  const int* tags = (const int*)d_in[4];
  const int* mask = (const int*)d_in[5];
  float* diff = (float*)d_ws;  // 256 floats
  float* out = (float*)d_out;

  crf_fb_kernel<<<BB, 256, 0, stream>>>(inputs, trans, start_t, end_t, tags,
                                        mask, diff);
  crf_sum_kernel<<<1, 256, 0, stream>>>(diff, out);
}